// Round 1
// baseline (73.676 us; speedup 1.0000x reference)
//
#include <hip/hip_runtime.h>

// SigmoidDVHLoss: per-(batch,label) mean of sigmoid((dose-thr)/0.1) for pred
// and target, then MSE over the 8x3 DVH entries.
//
// Shapes: pred/targ/mask = [8, 128,128,128]; ptv_values = [3]; out = scalar f32.

#define NB 8
#define NK 3
#define VPB (1 << 21)        // 128^3 voxels per batch
#define BLOCK 256
#define CHUNKS 512           // blocks per batch
#define VOX_PER_BLOCK (VPB / CHUNKS)   // 4096
#define NV4 (VOX_PER_BLOCK / 4)        // 1024 float4 per block

// ws layout (doubles): [0..23] sum_pred[b*3+k], [24..47] sum_targ, [48..71] count
#define WS_DOUBLES 72

__global__ __launch_bounds__(BLOCK) void dvh_sum_kernel(
    const float* __restrict__ pred,
    const float* __restrict__ targ,
    const int*   __restrict__ mask,
    const float* __restrict__ ptv,
    double*      __restrict__ ws)
{
    const int batch = blockIdx.x / CHUNKS;
    const int chunk = blockIdx.x % CHUNKS;
    const long base = (long)batch * VPB + (long)chunk * VOX_PER_BLOCK;

    const float4* __restrict__ p4 = (const float4*)(pred + base);
    const float4* __restrict__ t4 = (const float4*)(targ + base);
    const int4*   __restrict__ m4 = (const int4*)(mask + base);

    const float thr0 = ptv[0], thr1 = ptv[1], thr2 = ptv[2];

    // per-thread f32 partials (<=16 voxels each -> exact enough), counts int
    float sp0 = 0.f, sp1 = 0.f, sp2 = 0.f;
    float st0 = 0.f, st1 = 0.f, st2 = 0.f;
    int   c0 = 0,    c1 = 0,    c2 = 0;

    for (int i = threadIdx.x; i < NV4; i += BLOCK) {
        float4 p = p4[i];
        float4 t = t4[i];
        int4   m = m4[i];

        #define DO_ELEM(PJ, TJ, MJ)                                          \
        {                                                                    \
            int mm = (MJ);                                                   \
            float thr = (mm == 1) ? thr0 : ((mm == 2) ? thr1 : thr2);        \
            float sgp = 1.0f / (1.0f + expf((thr - (PJ)) * 10.0f));          \
            float sgt = 1.0f / (1.0f + expf((thr - (TJ)) * 10.0f));          \
            sp0 += (mm == 1) ? sgp : 0.0f;                                   \
            sp1 += (mm == 2) ? sgp : 0.0f;                                   \
            sp2 += (mm == 3) ? sgp : 0.0f;                                   \
            st0 += (mm == 1) ? sgt : 0.0f;                                   \
            st1 += (mm == 2) ? sgt : 0.0f;                                   \
            st2 += (mm == 3) ? sgt : 0.0f;                                   \
            c0  += (mm == 1) ? 1 : 0;                                        \
            c1  += (mm == 2) ? 1 : 0;                                        \
            c2  += (mm == 3) ? 1 : 0;                                        \
        }

        DO_ELEM(p.x, t.x, m.x)
        DO_ELEM(p.y, t.y, m.y)
        DO_ELEM(p.z, t.z, m.z)
        DO_ELEM(p.w, t.w, m.w)
        #undef DO_ELEM
    }

    // promote to double, wave(64)-reduce, then LDS across the 4 waves
    double v[9] = { (double)sp0, (double)sp1, (double)sp2,
                    (double)st0, (double)st1, (double)st2,
                    (double)c0,  (double)c1,  (double)c2 };

    #pragma unroll
    for (int q = 0; q < 9; ++q) {
        double x = v[q];
        #pragma unroll
        for (int off = 32; off > 0; off >>= 1)
            x += __shfl_down(x, off, 64);
        v[q] = x;
    }

    __shared__ double red[BLOCK / 64][9];
    const int wid  = threadIdx.x >> 6;
    const int lane = threadIdx.x & 63;
    if (lane == 0) {
        #pragma unroll
        for (int q = 0; q < 9; ++q) red[wid][q] = v[q];
    }
    __syncthreads();

    if (threadIdx.x < 9) {
        const int q = threadIdx.x;
        double s = red[0][q] + red[1][q] + red[2][q] + red[3][q];
        const int k   = q % 3;
        const int arr = q / 3;           // 0 = sum_pred, 1 = sum_targ, 2 = count
        atomicAdd(&ws[arr * (NB * NK) + batch * NK + k], s);
    }
}

__global__ __launch_bounds__(64) void dvh_finalize_kernel(
    const double* __restrict__ ws, float* __restrict__ out)
{
    const int i = threadIdx.x;
    double v = 0.0;
    if (i < NB * NK) {
        double sp = ws[i];
        double st = ws[NB * NK + i];
        double c  = ws[2 * NB * NK + i];
        double d  = sp / c - st / c;
        v = d * d;
    }
    #pragma unroll
    for (int off = 32; off > 0; off >>= 1)
        v += __shfl_down(v, off, 64);
    if (i == 0) out[0] = (float)(v / (double)(NB * NK));
}

extern "C" void kernel_launch(void* const* d_in, const int* in_sizes, int n_in,
                              void* d_out, int out_size, void* d_ws, size_t ws_size,
                              hipStream_t stream) {
    const float* pred = (const float*)d_in[0];
    const float* targ = (const float*)d_in[1];
    const int*   mask = (const int*)d_in[2];
    const float* ptv  = (const float*)d_in[3];
    float* out = (float*)d_out;
    double* ws = (double*)d_ws;

    hipMemsetAsync(ws, 0, WS_DOUBLES * sizeof(double), stream);

    dvh_sum_kernel<<<NB * CHUNKS, BLOCK, 0, stream>>>(pred, targ, mask, ptv, ws);
    dvh_finalize_kernel<<<1, 64, 0, stream>>>(ws, out);
}

// Round 2
// 66.284 us; speedup vs baseline: 1.1115x; 1.1115x over previous
//
#include <hip/hip_runtime.h>

// SigmoidDVHLoss: per-(batch,label) mean of sigmoid((dose-thr)/0.1) for pred
// and target, then MSE over the 8x3 DVH entries.
//
// loss = mean_{b,k} ( (sum_{m==k}(sig_p - sig_t)) / count_k )^2
// so we accumulate the per-voxel DIFFERENCE (3 slots) + counts (3 slots).
//
// Shapes: pred/targ/mask = [8, 128,128,128] f32/i32; ptv_values = [3] f32.

#define NB 8
#define NK 3
#define VPB (1 << 21)        // 128^3 voxels per batch
#define BLOCK 256
#define CHUNKS 512           // blocks per batch
#define VOX_PER_BLOCK (VPB / CHUNKS)   // 4096
#define NV4 (VOX_PER_BLOCK / 4)        // 1024 float4 per block

// ws layout (doubles): [0..23] sum_diff[b*3+k], [24..47] count[b*3+k]
#define WS_DOUBLES 48

#define LOG2E_X10 14.4269504088896341f   // 10 / ln(2)

__global__ __launch_bounds__(BLOCK) void dvh_sum_kernel(
    const float* __restrict__ pred,
    const float* __restrict__ targ,
    const int*   __restrict__ mask,
    const float* __restrict__ ptv,
    double*      __restrict__ ws)
{
    const int batch = blockIdx.x / CHUNKS;
    const int chunk = blockIdx.x % CHUNKS;
    const long base = (long)batch * VPB + (long)chunk * VOX_PER_BLOCK;

    const float4* __restrict__ p4 = (const float4*)(pred + base);
    const float4* __restrict__ t4 = (const float4*)(targ + base);
    const int4*   __restrict__ m4 = (const int4*)(mask + base);

    // scaled thresholds: sig = rcp(1 + 2^(thr*C - d*C))
    const float tc0 = ptv[0] * LOG2E_X10;
    const float tc1 = ptv[1] * LOG2E_X10;
    const float tc2 = ptv[2] * LOG2E_X10;

    float d0 = 0.f, d1 = 0.f, d2 = 0.f;   // sum of (sig_p - sig_t) per label
    int   c0 = 0,   c1 = 0,   c2 = 0;     // counts per label

    #pragma unroll
    for (int i = threadIdx.x; i < NV4; i += BLOCK) {
        float4 p = p4[i];
        float4 t = t4[i];
        int4   m = m4[i];

        #define DO_ELEM(PJ, TJ, MJ)                                          \
        {                                                                    \
            const int mm = (MJ);                                             \
            const bool is1 = (mm == 1), is2 = (mm == 2), is3 = (mm == 3);    \
            const float thrC = is1 ? tc0 : (is2 ? tc1 : tc2);                \
            const float ep = __builtin_amdgcn_exp2f(                         \
                                 __builtin_fmaf((PJ), -LOG2E_X10, thrC));    \
            const float et = __builtin_amdgcn_exp2f(                         \
                                 __builtin_fmaf((TJ), -LOG2E_X10, thrC));    \
            const float sgp = __builtin_amdgcn_rcpf(1.0f + ep);              \
            const float sgt = __builtin_amdgcn_rcpf(1.0f + et);              \
            const float df  = sgp - sgt;                                     \
            d0 += is1 ? df : 0.0f;                                           \
            d1 += is2 ? df : 0.0f;                                           \
            d2 += is3 ? df : 0.0f;                                           \
            c0 += is1 ? 1 : 0;                                               \
            c1 += is2 ? 1 : 0;                                               \
            c2 += is3 ? 1 : 0;                                               \
        }

        DO_ELEM(p.x, t.x, m.x)
        DO_ELEM(p.y, t.y, m.y)
        DO_ELEM(p.z, t.z, m.z)
        DO_ELEM(p.w, t.w, m.w)
        #undef DO_ELEM
    }

    // promote to double, wave(64)-reduce, then LDS across the 4 waves
    double v[6] = { (double)d0, (double)d1, (double)d2,
                    (double)c0, (double)c1, (double)c2 };

    #pragma unroll
    for (int q = 0; q < 6; ++q) {
        double x = v[q];
        #pragma unroll
        for (int off = 32; off > 0; off >>= 1)
            x += __shfl_down(x, off, 64);
        v[q] = x;
    }

    __shared__ double red[BLOCK / 64][6];
    const int wid  = threadIdx.x >> 6;
    const int lane = threadIdx.x & 63;
    if (lane == 0) {
        #pragma unroll
        for (int q = 0; q < 6; ++q) red[wid][q] = v[q];
    }
    __syncthreads();

    if (threadIdx.x < 6) {
        const int q = threadIdx.x;
        double s = red[0][q] + red[1][q] + red[2][q] + red[3][q];
        const int k   = q % 3;
        const int arr = q / 3;           // 0 = sum_diff, 1 = count
        atomicAdd(&ws[arr * (NB * NK) + batch * NK + k], s);
    }
}

__global__ __launch_bounds__(64) void dvh_finalize_kernel(
    const double* __restrict__ ws, float* __restrict__ out)
{
    const int i = threadIdx.x;
    double v = 0.0;
    if (i < NB * NK) {
        double sd = ws[i];
        double c  = ws[NB * NK + i];
        double d  = sd / c;
        v = d * d;
    }
    #pragma unroll
    for (int off = 32; off > 0; off >>= 1)
        v += __shfl_down(v, off, 64);
    if (i == 0) out[0] = (float)(v / (double)(NB * NK));
}

extern "C" void kernel_launch(void* const* d_in, const int* in_sizes, int n_in,
                              void* d_out, int out_size, void* d_ws, size_t ws_size,
                              hipStream_t stream) {
    const float* pred = (const float*)d_in[0];
    const float* targ = (const float*)d_in[1];
    const int*   mask = (const int*)d_in[2];
    const float* ptv  = (const float*)d_in[3];
    float* out = (float*)d_out;
    double* ws = (double*)d_ws;

    hipMemsetAsync(ws, 0, WS_DOUBLES * sizeof(double), stream);

    dvh_sum_kernel<<<NB * CHUNKS, BLOCK, 0, stream>>>(pred, targ, mask, ptv, ws);
    dvh_finalize_kernel<<<1, 64, 0, stream>>>(ws, out);
}

// Round 3
// 62.837 us; speedup vs baseline: 1.1725x; 1.0549x over previous
//
#include <hip/hip_runtime.h>

// SigmoidDVHLoss: per-(batch,label) mean of sigmoid((dose-thr)/0.1) for pred
// and target, then MSE over the 8x3 DVH entries.
//
// loss = mean_{b,k} ( (sum_{m==k}(sig_p - sig_t)) / count_k )^2
//
// R2: load-latency bound fix — all 12 float4/int4 loads per thread hoisted
// up-front (independent, in-flight together) before any compute. R1's loop
// form compiled to VGPR=16 with serialized load->wait->compute.

#define NB 8
#define NK 3
#define VPB (1 << 21)        // 128^3 voxels per batch
#define BLOCK 256
#define CHUNKS 512           // blocks per batch
#define VOX_PER_BLOCK (VPB / CHUNKS)   // 4096 voxels = 1024 float4
#define NV4 (VOX_PER_BLOCK / 4)        // 1024

// ws layout (doubles): [0..23] sum_diff[b*3+k], [24..47] count[b*3+k]
#define WS_DOUBLES 48

#define LOG2E_X10 14.4269504088896341f   // 10 / ln(2)

__global__ __launch_bounds__(BLOCK) void dvh_sum_kernel(
    const float* __restrict__ pred,
    const float* __restrict__ targ,
    const int*   __restrict__ mask,
    const float* __restrict__ ptv,
    double*      __restrict__ ws)
{
    const int batch = blockIdx.x / CHUNKS;
    const int chunk = blockIdx.x % CHUNKS;
    const long base = (long)batch * VPB + (long)chunk * VOX_PER_BLOCK;

    const float4* __restrict__ p4 = (const float4*)(pred + base);
    const float4* __restrict__ t4 = (const float4*)(targ + base);
    const int4*   __restrict__ m4 = (const int4*)(mask + base);

    const int tid = threadIdx.x;

    // ---- issue all 12 loads up-front (independent, stay in flight) ----
    const float4 p0 = p4[tid];
    const float4 p1 = p4[tid + BLOCK];
    const float4 p2 = p4[tid + 2 * BLOCK];
    const float4 p3 = p4[tid + 3 * BLOCK];
    const float4 t0 = t4[tid];
    const float4 t1 = t4[tid + BLOCK];
    const float4 t2 = t4[tid + 2 * BLOCK];
    const float4 t3 = t4[tid + 3 * BLOCK];
    const int4   m0 = m4[tid];
    const int4   m1 = m4[tid + BLOCK];
    const int4   m2 = m4[tid + 2 * BLOCK];
    const int4   m3 = m4[tid + 3 * BLOCK];

    // scaled thresholds: sig = rcp(1 + 2^(thr*C - d*C))
    const float tc0 = ptv[0] * LOG2E_X10;
    const float tc1 = ptv[1] * LOG2E_X10;
    const float tc2 = ptv[2] * LOG2E_X10;

    float d0 = 0.f, d1 = 0.f, d2 = 0.f;   // sum of (sig_p - sig_t) per label
    int   c0 = 0,   c1 = 0,   c2 = 0;     // counts per label

    #define DO_ELEM(PJ, TJ, MJ)                                          \
    {                                                                    \
        const int mm = (MJ);                                             \
        const bool is1 = (mm == 1), is2 = (mm == 2), is3 = (mm == 3);    \
        const float thrC = is1 ? tc0 : (is2 ? tc1 : tc2);                \
        const float ep = __builtin_amdgcn_exp2f(                         \
                             __builtin_fmaf((PJ), -LOG2E_X10, thrC));    \
        const float et = __builtin_amdgcn_exp2f(                         \
                             __builtin_fmaf((TJ), -LOG2E_X10, thrC));    \
        const float sgp = __builtin_amdgcn_rcpf(1.0f + ep);              \
        const float sgt = __builtin_amdgcn_rcpf(1.0f + et);              \
        const float df  = sgp - sgt;                                     \
        d0 += is1 ? df : 0.0f;                                           \
        d1 += is2 ? df : 0.0f;                                           \
        d2 += is3 ? df : 0.0f;                                           \
        c0 += is1 ? 1 : 0;                                               \
        c1 += is2 ? 1 : 0;                                               \
        c2 += is3 ? 1 : 0;                                               \
    }

    #define DO_VEC4(P, T, M)                                             \
        DO_ELEM(P.x, T.x, M.x)                                           \
        DO_ELEM(P.y, T.y, M.y)                                           \
        DO_ELEM(P.z, T.z, M.z)                                           \
        DO_ELEM(P.w, T.w, M.w)

    DO_VEC4(p0, t0, m0)
    DO_VEC4(p1, t1, m1)
    DO_VEC4(p2, t2, m2)
    DO_VEC4(p3, t3, m3)
    #undef DO_VEC4
    #undef DO_ELEM

    // promote to double, wave(64)-reduce, then LDS across the 4 waves
    double v[6] = { (double)d0, (double)d1, (double)d2,
                    (double)c0, (double)c1, (double)c2 };

    #pragma unroll
    for (int q = 0; q < 6; ++q) {
        double x = v[q];
        #pragma unroll
        for (int off = 32; off > 0; off >>= 1)
            x += __shfl_down(x, off, 64);
        v[q] = x;
    }

    __shared__ double red[BLOCK / 64][6];
    const int wid  = threadIdx.x >> 6;
    const int lane = threadIdx.x & 63;
    if (lane == 0) {
        #pragma unroll
        for (int q = 0; q < 6; ++q) red[wid][q] = v[q];
    }
    __syncthreads();

    if (threadIdx.x < 6) {
        const int q = threadIdx.x;
        double s = red[0][q] + red[1][q] + red[2][q] + red[3][q];
        const int k   = q % 3;
        const int arr = q / 3;           // 0 = sum_diff, 1 = count
        atomicAdd(&ws[arr * (NB * NK) + batch * NK + k], s);
    }
}

__global__ __launch_bounds__(64) void dvh_finalize_kernel(
    const double* __restrict__ ws, float* __restrict__ out)
{
    const int i = threadIdx.x;
    double v = 0.0;
    if (i < NB * NK) {
        double sd = ws[i];
        double c  = ws[NB * NK + i];
        double d  = sd / c;
        v = d * d;
    }
    #pragma unroll
    for (int off = 32; off > 0; off >>= 1)
        v += __shfl_down(v, off, 64);
    if (i == 0) out[0] = (float)(v / (double)(NB * NK));
}

extern "C" void kernel_launch(void* const* d_in, const int* in_sizes, int n_in,
                              void* d_out, int out_size, void* d_ws, size_t ws_size,
                              hipStream_t stream) {
    const float* pred = (const float*)d_in[0];
    const float* targ = (const float*)d_in[1];
    const int*   mask = (const int*)d_in[2];
    const float* ptv  = (const float*)d_in[3];
    float* out = (float*)d_out;
    double* ws = (double*)d_ws;

    hipMemsetAsync(ws, 0, WS_DOUBLES * sizeof(double), stream);

    dvh_sum_kernel<<<NB * CHUNKS, BLOCK, 0, stream>>>(pred, targ, mask, ptv, ws);
    dvh_finalize_kernel<<<1, 64, 0, stream>>>(ws, out);
}